// Round 1
// baseline (5984.808 us; speedup 1.0000x reference)
//
#include <hip/hip_runtime.h>

// ReLU-RNN: B=8192, T=1024, I=7, H=100, O=1
// h_t = relu(x_t @ W_ih^T + b_ih + b_hh + h_{t-1} @ W_hh^T); out = h_T @ W_fc^T + b_fc
//
// Design: persistent recurrence per block. Block = 256 threads = 16 batches x 16
// h-chunks (7 rows each). Grid = 512 blocks -> 2 blocks/CU, 2 waves/SIMD.
// h_prev register-resident per thread (100 VGPRs); W_hh streamed from LDS
// (4 distinct row addresses per wave inst, conflict-free, 16-lane broadcast);
// h exchanged via double-buffered LDS (one __syncthreads per step).

#define TT 1024
#define II 7
#define HH 100
#define BB 16   // batches per block
#define CH 7    // h rows per thread (16 chunks x 7 = 112 >= 100)

__global__ __launch_bounds__(256, 2)
void rnn_persist(const float* __restrict__ x,
                 const float* __restrict__ W_ih,
                 const float* __restrict__ W_hh,
                 const float* __restrict__ b_ih,
                 const float* __restrict__ b_hh,
                 const float* __restrict__ W_fc,
                 const float* __restrict__ b_fc,
                 float* __restrict__ out) {
    __shared__ float Wlds[HH * HH];        // 40000 B, row-major, stride 100
    __shared__ float hbuf[2][BB][HH];      // 12800 B double-buffered h state
    __shared__ float wfc_lds[HH];

    const int tid = threadIdx.x;
    const int b   = tid & 15;    // batch within block (low bits -> wave = 16b x 4c)
    const int c   = tid >> 4;    // h-chunk index [0,16)
    const int bg  = blockIdx.x * BB + b;   // global batch

    // Stage W_hh and W_fc into LDS (once; amortized over 1024 steps)
    for (int idx = tid; idx < HH * HH; idx += 256) Wlds[idx] = W_hh[idx];
    if (tid < HH) wfc_lds[tid] = W_fc[tid];
    __syncthreads();

    // Per-thread row chunk: W_ih rows + combined bias in registers (static)
    const int h0 = c * CH;
    float wih[CH][II];
    float bias[CH];
    int rowbase[CH];
#pragma unroll
    for (int k = 0; k < CH; ++k) {
        int h  = h0 + k;
        int hc = (h < HH) ? h : (HH - 1);   // clamp: pad threads duplicate row 99
        rowbase[k] = hc * HH;
#pragma unroll
        for (int i = 0; i < II; ++i) wih[k][i] = W_ih[hc * II + i];
        bias[k] = b_ih[hc] + b_hh[hc];
    }

    // h_prev in registers, replicated across the 16 chunk-threads of this batch
    float hp[HH];
#pragma unroll
    for (int j = 0; j < HH; ++j) hp[j] = 0.f;

    const float* xb = x + (size_t)bg * TT * II;
    float xr[II];
#pragma unroll
    for (int i = 0; i < II; ++i) xr[i] = xb[i];   // t = 0

    int cur = 0;
    for (int t = 0; t < TT; ++t) {
        // Prefetch next timestep's x (independent of FMAs below; clamped in-bounds)
        const int tn = (t + 1 < TT) ? (t + 1) : (TT - 1);
        float xn[II];
#pragma unroll
        for (int i = 0; i < II; ++i) xn[i] = xb[tn * II + i];

        // Compute this thread's 7 h-outputs
#pragma unroll
        for (int k = 0; k < CH; ++k) {
            const float* wrow = &Wlds[rowbase[k]];
            float a0 = bias[k], a1 = 0.f, a2 = 0.f, a3 = 0.f;
#pragma unroll
            for (int i = 0; i < II; ++i) a0 = fmaf(wih[k][i], xr[i], a0);
#pragma unroll
            for (int j = 0; j < HH; j += 4) {
                float4 w = *(const float4*)(wrow + j);   // ds_read_b128, 4 distinct addrs/wave
                a0 = fmaf(w.x, hp[j + 0], a0);
                a1 = fmaf(w.y, hp[j + 1], a1);
                a2 = fmaf(w.z, hp[j + 2], a2);
                a3 = fmaf(w.w, hp[j + 3], a3);
            }
            float s = (a0 + a1) + (a2 + a3);
            s = (s > 0.f) ? s : 0.f;                      // relu
            int h = h0 + k;
            if (h < HH) hbuf[cur][b][h] = s;              // conflict-free scatter
        }

        __syncthreads();   // all hnew written; double-buffer makes 1 barrier enough

        // Reload full h into registers (stride-100 float4: 2-way aliasing = free)
#pragma unroll
        for (int j = 0; j < HH; j += 4) {
            float4 v = *(const float4*)&hbuf[cur][b][j];
            hp[j + 0] = v.x; hp[j + 1] = v.y; hp[j + 2] = v.z; hp[j + 3] = v.w;
        }
#pragma unroll
        for (int i = 0; i < II; ++i) xr[i] = xn[i];
        cur ^= 1;
    }

    // Epilogue: every thread holds the full final h for its batch; chunk 0 does fc
    if (c == 0) {
        float acc = b_fc[0];
#pragma unroll
        for (int j = 0; j < HH; ++j) acc = fmaf(wfc_lds[j], hp[j], acc);
        out[bg] = acc;
    }
}

extern "C" void kernel_launch(void* const* d_in, const int* in_sizes, int n_in,
                              void* d_out, int out_size, void* d_ws, size_t ws_size,
                              hipStream_t stream) {
    const float* x    = (const float*)d_in[0];
    const float* W_ih = (const float*)d_in[1];
    const float* W_hh = (const float*)d_in[2];
    const float* b_ih = (const float*)d_in[3];
    const float* b_hh = (const float*)d_in[4];
    const float* W_fc = (const float*)d_in[5];
    const float* b_fc = (const float*)d_in[6];
    float* out = (float*)d_out;

    dim3 grid(512), block(256);
    rnn_persist<<<grid, block, 0, stream>>>(x, W_ih, W_hh, b_ih, b_hh, W_fc, b_fc, out);
}

// Round 2
// 735.529 us; speedup vs baseline: 8.1367x; 8.1367x over previous
//
#include <hip/hip_runtime.h>

// ReLU-RNN B=8192, T=1024, I=7, H=100, O=1 via f16 MFMA recurrence.
//
// h_t[m][n] = relu( sum_k A_aug[m][k] * W_aug[n][k] ),  K augmented to 128:
//   k in [0,100): h_{t-1}   [100,107): x_t   k==107: 1.0 (bias)   [108,128): 0
//   W_aug[n][k]: W_hh | W_ih | (b_ih+b_hh) | 0   -- constant, lives in VGPRs.
//
// We compute D[n][m] = W_aug · H^T with mfma_f32_16x16x32_f16 (A=W, B=H) so the
// C/D layout (col=lane&15 -> batch m, row=quad*4+reg -> n) gives each lane 4
// CONSECUTIVE n for one batch row -> single b64 LDS write per tile.
//
// 512 blocks x 128 thr: block owns 16 batch rows for all 1024 steps (rows are
// independent -> no inter-block traffic). 2 waves split the 7 N-tiles (+1 dup
// for balance). H double-buffered in LDS (stride 136 f16: bank-uniform reads).
// x prefetched with a depth-8 register pipeline; barriers are raw
// "s_waitcnt lgkmcnt(0); s_barrier" so in-flight x loads are NOT drained
// (HIP __syncthreads would emit vmcnt(0) and serialize the prefetch).

typedef _Float16 half8 __attribute__((ext_vector_type(8)));
typedef float f32x4 __attribute__((ext_vector_type(4)));
typedef unsigned u32x2 __attribute__((ext_vector_type(2)));

#define BAR() __asm__ volatile("s_waitcnt lgkmcnt(0)\n\ts_barrier" ::: "memory")

static __device__ __forceinline__ unsigned pkrtz(float a, float b) {
    auto p = __builtin_amdgcn_cvt_pkrtz(a, b);   // v2f16, round-to-zero
    return __builtin_bit_cast(unsigned, p);
}

__global__ __launch_bounds__(128, 1)
void rnn_mfma(const float* __restrict__ x,
              const float* __restrict__ W_ih,
              const float* __restrict__ W_hh,
              const float* __restrict__ b_ih,
              const float* __restrict__ b_hh,
              const float* __restrict__ W_fc,
              const float* __restrict__ b_fc,
              float* __restrict__ out) {
    __shared__ __align__(16) _Float16 Hbuf[2][16][136];  // [buf][m][k], pad 128->136

    const int tid = threadIdx.x;
    const int wv  = tid >> 6;        // wave 0 or 1
    const int l   = tid & 63;
    const int lm  = l & 15;          // MFMA "lane&15" index
    const int q   = l >> 4;          // quad

    // ---- zero both H buffers (h0 = 0, K-pad = 0) ----
    {
        unsigned* hz = (unsigned*)&Hbuf[0][0][0];
        for (int i = tid; i < 2 * 16 * 136 / 2; i += 128) hz[i] = 0u;
    }
    __syncthreads();
    // bias-one slot k=107 in both buffers
    if (tid < 32) Hbuf[tid >> 4][tid & 15][107] = (_Float16)1.0f;

    // ---- constant W_aug fragments in registers (A-operand) ----
    // wave0: n-tiles 0..3 (tile 3 duplicated, not stored); wave1: n-tiles 3..6
    const int ntBase = wv ? 3 : 0;
    half8 wfrag[4][4];               // [tile][kt]
#pragma unroll
    for (int ti = 0; ti < 4; ++ti) {
        const int n = (ntBase + ti) * 16 + lm;
        float bsum = 0.f;
        if (n < 100) bsum = b_ih[n] + b_hh[n];
#pragma unroll
        for (int kt = 0; kt < 4; ++kt) {
            half8 w;
#pragma unroll
            for (int jj = 0; jj < 8; ++jj) {
                const int k = kt * 32 + q * 8 + jj;
                float v = 0.f;
                if (n < 100) {
                    if (k < 100)       v = W_hh[n * 100 + k];
                    else if (k < 107)  v = W_ih[n * 7 + (k - 100)];
                    else if (k == 107) v = bsum;
                }
                w[jj] = (_Float16)v;
            }
            wfrag[ti][kt] = w;
        }
    }

    // ---- x addressing for the stager (wave 0): lane -> (row, dword pair) ----
    const int xrow = l >> 2;                 // 0..15
    const int xp   = l & 3;                  // pair 0..3 (i = 2p, 2p+1; p3 -> i=6)
    const long rowg = (long)blockIdx.x * 16 + xrow;
    const float* xpA = x + rowg * 7168 + (xp < 3 ? 2 * xp : 6);
    const float* xpB = (xp < 3) ? xpA + 1 : xpA;   // p3: duplicate (avoid OOB)

    // x_0 into buf0 (synchronous, pre-loop)
    if (wv == 0) {
        float a0 = xpA[0], b0 = xpB[0];
        if (xp < 3) *(unsigned*)&Hbuf[0][xrow][100 + 2 * xp] = pkrtz(a0, b0);
        else        Hbuf[0][xrow][106] = (_Float16)a0;
    }
    __syncthreads();   // prologue done (this one may drain vmcnt -- one-time)

    // ---- depth-8 x prefetch pipeline: slot u holds x_{t+1} for steps t==u mod 8
    float xa[8], xb[8];
    if (wv == 0) {
#pragma unroll
        for (int u = 0; u < 8; ++u) {
            const int tt = u + 1;
            xa[u] = xpA[(size_t)tt * 7];
            xb[u] = xpB[(size_t)tt * 7];
        }
    }

    // ---- main recurrence ----
    for (int tb = 0; tb < 1024; tb += 8) {
#pragma unroll
        for (int u = 0; u < 8; ++u) {
            const int t  = tb + u;
            const int cb = u & 1;        // read buffer (t even -> 0)
            const int nb = cb ^ 1;       // write buffer

            // B-operand: H rows (this block's batch), full K
            half8 hfrag[4];
#pragma unroll
            for (int kt = 0; kt < 4; ++kt)
                hfrag[kt] = *(const half8*)&Hbuf[cb][lm][kt * 32 + q * 8];

            // D[n][m] accumulate, kt-outer for 4 independent chains
            f32x4 acc[4] = {{0,0,0,0},{0,0,0,0},{0,0,0,0},{0,0,0,0}};
#pragma unroll
            for (int kt = 0; kt < 4; ++kt) {
#pragma unroll
                for (int ti = 0; ti < 4; ++ti)
                    acc[ti] = __builtin_amdgcn_mfma_f32_16x16x32_f16(
                        wfrag[ti][kt], hfrag[kt], acc[ti], 0, 0, 0);
            }

            // relu + f16 pack + b64 store: lane writes 4 consecutive n at row lm
#pragma unroll
            for (int ti = 0; ti < 4; ++ti) {
                const int nt = ntBase + ti;
                const bool own = wv ? (ti < 3 || q == 0)   // tile6: n=96..99 only
                                    : (ti < 3);            // wave0 tile3 is dup
                if (own) {
                    f32x4 a = acc[ti];
                    u32x2 uu;
                    uu.x = pkrtz(fmaxf(a[0], 0.f), fmaxf(a[1], 0.f));
                    uu.y = pkrtz(fmaxf(a[2], 0.f), fmaxf(a[3], 0.f));
                    *(u32x2*)&Hbuf[nb][lm][nt * 16 + q * 4] = uu;
                }
            }

            // x staging: write x_{t+1} (slot u) to buf nb, reissue for t+9
            if (wv == 0) {
                if (t < 1023) {
                    if (xp < 3) *(unsigned*)&Hbuf[nb][xrow][100 + 2 * xp] = pkrtz(xa[u], xb[u]);
                    else        Hbuf[nb][xrow][106] = (_Float16)xa[u];
                }
                int tt = t + 9; if (tt > 1023) tt = 1023;
                xa[u] = xpA[(size_t)tt * 7];
                xb[u] = xpB[(size_t)tt * 7];
            }

            BAR();   // lgkmcnt(0) + s_barrier; vmcnt NOT drained (keep x in flight)
        }
    }

    // ---- fc epilogue: h_1023 is in buf 0 ----
    if (tid < 16) {
        float s = b_fc[0];
#pragma unroll 4
        for (int j = 0; j < 100; ++j)
            s += (float)Hbuf[0][tid][j] * W_fc[j];
        out[blockIdx.x * 16 + tid] = s;
    }
}

extern "C" void kernel_launch(void* const* d_in, const int* in_sizes, int n_in,
                              void* d_out, int out_size, void* d_ws, size_t ws_size,
                              hipStream_t stream) {
    const float* x    = (const float*)d_in[0];
    const float* W_ih = (const float*)d_in[1];
    const float* W_hh = (const float*)d_in[2];
    const float* b_ih = (const float*)d_in[3];
    const float* b_hh = (const float*)d_in[4];
    const float* W_fc = (const float*)d_in[5];
    const float* b_fc = (const float*)d_in[6];
    float* out = (float*)d_out;

    rnn_mfma<<<dim3(512), dim3(128), 0, stream>>>(x, W_ih, W_hh, b_ih, b_hh, W_fc, b_fc, out);
}

// Round 3
// 619.674 us; speedup vs baseline: 9.6580x; 1.1870x over previous
//
#include <hip/hip_runtime.h>

// ReLU-RNN B=8192, T=1024, I=7, H=100, O=1 — barrier-free MFMA recurrence.
//
// Per wave: 16 batch rows, all of H, all 1024 steps. The state lives in a
// PERMUTED index space chosen so the MFMA D-layout of step t is exactly the
// B-fragment layout of step t+1 on the same lane:
//   D position (ti, q, r)  [n' = 16ti+4q+r, batch m = lane&15]
//   maps to B slot k' = 32kt + 8q + jj with
//      ti<4 : kt=ti,   jj=r        ti>=4: kt=ti-4, jj=4+r
// W' is built once per lane with rows n' and columns pre-permuted by the same
// map, so the recurrence is exact in permuted space. The 16 unused k' slots
// (kt=3, jj>=4) carry x_t (7 floats) and the bias constant 1.0:
//   q=0 supplies k'=100..103 -> x0..x3 ; q=1 supplies 108..111 -> x4,x5,x6,1.0
// => main loop = 28 MFMA + in-register relu/pack + 4 prefetched x loads.
//    NO LDS, NO barrier, NO cross-lane data movement.
//
// Grid: 512 blocks x 64 threads (1 wave) = 2 waves/CU. W fragments: 112 VGPRs.

typedef _Float16 half8 __attribute__((ext_vector_type(8)));
typedef float f32x4 __attribute__((ext_vector_type(4)));
typedef unsigned u32x4 __attribute__((ext_vector_type(4)));

static __device__ __forceinline__ unsigned pkrtz(float a, float b) {
    return __builtin_bit_cast(unsigned, __builtin_amdgcn_cvt_pkrtz(a, b));
}

__global__ __launch_bounds__(64, 1)
void rnn_wave(const float* __restrict__ x,
              const float* __restrict__ W_ih,
              const float* __restrict__ W_hh,
              const float* __restrict__ b_ih,
              const float* __restrict__ b_hh,
              const float* __restrict__ W_fc,
              const float* __restrict__ b_fc,
              float* __restrict__ out) {
    const int l  = threadIdx.x;
    const int lm = l & 15;           // batch row within tile
    const int q  = l >> 4;           // quad
    const bool q1   = (q == 1);
    const bool qlt2 = (q < 2);

    // ---- W' fragments (constant for all 1024 steps; 7 tiles x 4 kt) ----
    half8 w[7][4];
#pragma unroll
    for (int ti = 0; ti < 7; ++ti) {
        const int np = 16 * ti + lm;                  // output row n'
#pragma unroll
        for (int kt = 0; kt < 4; ++kt) {
            half8 hw;
#pragma unroll
            for (int jj = 0; jj < 8; ++jj) {
                float v = 0.f;
                if (np < 100) {
                    if (jj < 4) {                     // h slot, p = 16kt+4q+jj
                        int p = 16 * kt + 4 * q + jj;
                        if (p < 100) v = W_hh[np * 100 + p];
                    } else if (kt < 3) {              // h slot, p = 16(kt+4)+4q+(jj-4)
                        int p = 16 * (kt + 4) + 4 * q + (jj - 4);
                        if (p < 100) v = W_hh[np * 100 + p];
                    } else {                          // kt==3, jj>=4: x / bias slots
                        if (q == 0)      v = W_ih[np * 7 + (jj - 4)];      // x0..x3
                        else if (q == 1) v = (jj < 7) ? W_ih[np * 7 + jj]  // x4..x6
                                             : (b_ih[np] + b_hh[np]);     // bias @ jj=7
                    }
                }
                hw[jj] = (_Float16)v;
            }
            w[ti][kt] = hw;
        }
    }

    // ---- x addressing: lane loads only the dwords it supplies ----
    const float* xr = x + (size_t)(blockIdx.x * 16 + lm) * 7168;
    const int o0 = q1 ? 4 : 0, o1 = o0 + 1, o2 = o0 + 2, o3 = q1 ? 6 : 3;

    // hfrag for t=0: h=0 everywhere, x_0/bias in kt=3 tail
    half8 hf[4];
    {
        float v0 = xr[o0], v1 = xr[o1], v2 = xr[o2], v3 = xr[o3];
        u32x4 z = {0u, 0u, 0u, 0u};
        hf[0] = __builtin_bit_cast(half8, z);
        hf[1] = hf[0];
        hf[2] = hf[0];
        unsigned xd0 = pkrtz(v0, v1);
        unsigned xd1 = pkrtz(v2, q1 ? 1.0f : v3);
        if (!qlt2) { xd0 = 0u; xd1 = 0u; }
        u32x4 h3 = {0u, 0u, xd0, xd1};
        hf[3] = __builtin_bit_cast(half8, h3);
    }

    // depth-4 x prefetch: slot s&3 holds x_s
    float xv[4][4];
#pragma unroll
    for (int s = 1; s <= 4; ++s) {
        const float* p = xr + s * 7;
        xv[s & 3][0] = p[o0]; xv[s & 3][1] = p[o1];
        xv[s & 3][2] = p[o2]; xv[s & 3][3] = p[o3];
    }

    const f32x4 kZ = {0.f, 0.f, 0.f, 0.f};
    f32x4 acc[7];

    for (int tb = 0; tb < 1024; tb += 4) {
#pragma unroll
        for (int u = 0; u < 4; ++u) {
            const int t = tb + u;

            // 28 MFMAs; chains spaced 7 apart. Order {0,4,1,5,2,6,3} so the
            // chains feeding hf[0] (acc0/acc4) retire earliest.
#pragma unroll
            for (int kt = 0; kt < 4; ++kt) {
                const int order[7] = {0, 4, 1, 5, 2, 6, 3};
#pragma unroll
                for (int oi = 0; oi < 7; ++oi) {
                    const int ti = order[oi];
                    acc[ti] = __builtin_amdgcn_mfma_f32_16x16x32_f16(
                        w[ti][kt], hf[kt], (kt == 0) ? kZ : acc[ti], 0, 0, 0);
                }
            }

            // in-register repack: D -> next B fragment (relu + f16 pack)
            const int s = (u + 1) & 3;
#pragma unroll
            for (int kt = 0; kt < 3; ++kt) {
                u32x4 d;
                d.x = pkrtz(fmaxf(acc[kt][0], 0.f),     fmaxf(acc[kt][1], 0.f));
                d.y = pkrtz(fmaxf(acc[kt][2], 0.f),     fmaxf(acc[kt][3], 0.f));
                d.z = pkrtz(fmaxf(acc[kt + 4][0], 0.f), fmaxf(acc[kt + 4][1], 0.f));
                d.w = pkrtz(fmaxf(acc[kt + 4][2], 0.f), fmaxf(acc[kt + 4][3], 0.f));
                hf[kt] = __builtin_bit_cast(half8, d);
            }
            {
                unsigned xd0 = pkrtz(xv[s][0], xv[s][1]);
                unsigned xd1 = pkrtz(xv[s][2], q1 ? 1.0f : xv[s][3]);
                if (!qlt2) { xd0 = 0u; xd1 = 0u; }
                u32x4 d;
                d.x = pkrtz(fmaxf(acc[3][0], 0.f), fmaxf(acc[3][1], 0.f));
                d.y = pkrtz(fmaxf(acc[3][2], 0.f), fmaxf(acc[3][3], 0.f));
                d.z = xd0; d.w = xd1;
                hf[3] = __builtin_bit_cast(half8, d);
            }

            // refill slot s with x_{t+5} (used 4 steps from now)
            int tn = t + 5; if (tn > 1023) tn = 1023;
            const float* p = xr + tn * 7;
            xv[s][0] = p[o0]; xv[s][1] = p[o1];
            xv[s][2] = p[o2]; xv[s][3] = p[o3];
        }
    }

    // ---- epilogue: acc holds pre-relu h_T (permuted space, batch = lm) ----
    float sum = 0.f;
#pragma unroll
    for (int ti = 0; ti < 7; ++ti) {
#pragma unroll
        for (int r = 0; r < 4; ++r) {
            const int np = 16 * ti + 4 * q + r;
            const float wf = (np < 100) ? W_fc[np] : 0.f;
            sum += wf * fmaxf(acc[ti][r], 0.f);
        }
    }
    sum += __shfl_xor(sum, 16, 64);   // reduce across the 4 q-lanes of row lm
    sum += __shfl_xor(sum, 32, 64);
    if (q == 0) out[blockIdx.x * 16 + lm] = sum + b_fc[0];
}

extern "C" void kernel_launch(void* const* d_in, const int* in_sizes, int n_in,
                              void* d_out, int out_size, void* d_ws, size_t ws_size,
                              hipStream_t stream) {
    const float* x    = (const float*)d_in[0];
    const float* W_ih = (const float*)d_in[1];
    const float* W_hh = (const float*)d_in[2];
    const float* b_ih = (const float*)d_in[3];
    const float* b_hh = (const float*)d_in[4];
    const float* W_fc = (const float*)d_in[5];
    const float* b_fc = (const float*)d_in[6];
    float* out = (float*)d_out;

    rnn_wave<<<dim3(512), dim3(64), 0, stream>>>(x, W_ih, W_hh, b_ih, b_hh, W_fc, b_fc, out);
}